// Round 2
// baseline (470.552 us; speedup 1.0000x reference)
//
#include <hip/hip_runtime.h>

#define B_   512
#define C_   256
#define HWD_ 384
#define KC_  8      // K chunks of 32 (K = C = 256)
#define IT_  16     // 256/16 i-tiles
#define NT_  24     // 384/16 n-tiles

typedef __bf16 bf16x8 __attribute__((ext_vector_type(8)));
typedef float  f32x4  __attribute__((ext_vector_type(4)));

// ws layout (bytes):
//   cadj : f32 [B_][C_]                      @ 0            (512 KB)
//   Afrag: bf16 [B_][KC_][IT_][64 lanes][8]  @ 512K         (64 MB)
//   Bfrag: bf16 [B_][KC_][NT_][64 lanes][8]  @ 512K + 64M   (96 MB)
// Fragment chunk = 1 KB, lane = quad*16+lm holds 8 contiguous-k bf16:
//   A chunk (b,kc,it):  A[i=it*16+lm][k=kc*32+quad*8+j]
//   B chunk (b,kc,nt):  fea[k=kc*32+quad*8+j][n=nt*16+lm]
#define CADJ_BYTES  ((size_t)B_ * C_ * 4)
#define AFRAG_BYTES ((size_t)B_ * KC_ * IT_ * 1024)
#define BFRAG_BYTES ((size_t)B_ * KC_ * NT_ * 1024)
#define WS_NEEDED   (CADJ_BYTES + AFRAG_BYTES + BFRAG_BYTES)

// ---- kernel 1: x -> Bfrag (bf16, fragment order) + per-(b,c) mean, x read ONCE
__global__ __launch_bounds__(256) void bprep_kernel(const float* __restrict__ x,
                                                    float* __restrict__ cadj,
                                                    bf16x8* __restrict__ bfrag) {
    const int b = blockIdx.x, kc = blockIdx.y;
    const int t = threadIdx.x, lane = t & 63, w = t >> 6;
    const int quad = lane >> 4, lm = lane & 15;

    // this thread's 8 fixed channels: k = kc*32 + quad*8 + j
    const float* xb = x + ((size_t)b * C_ + kc * 32 + quad * 8) * HWD_ + lm;
    bf16x8* dst = bfrag + ((size_t)(b * KC_ + kc) * NT_) * 64 + lane;

    float acc[8];
#pragma unroll
    for (int j = 0; j < 8; ++j) acc[j] = 0.f;

#pragma unroll
    for (int ss = 0; ss < 6; ++ss) {
        const int nt = w + 4 * ss;               // wave w covers nt = w, w+4, ..., w+20
        const float* p = xb + nt * 16;
        bf16x8 pk;
#pragma unroll
        for (int j = 0; j < 8; ++j) {
            float v = p[(size_t)j * HWD_];       // 16-lane coalesced (n contiguous)
            acc[j] += v;
            pk[j] = (__bf16)v;
        }
        dst[(size_t)nt * 64] = pk;               // coalesced 16 B/lane store
    }

    // reduce over the 16 lm lanes within each quad group
#pragma unroll
    for (int m = 1; m < 16; m <<= 1)
#pragma unroll
        for (int j = 0; j < 8; ++j) acc[j] += __shfl_xor(acc[j], m, 64);

    __shared__ float red[128];                   // [wave][quad][j]
    if (lm == 0)
#pragma unroll
        for (int j = 0; j < 8; ++j) red[w * 32 + quad * 8 + j] = acc[j];
    __syncthreads();
    if (t < 32) {                                // t = quad*8 + j -> k_local
        float s = 0.f;
#pragma unroll
        for (int w2 = 0; w2 < 4; ++w2) s += red[w2 * 32 + t];
        cadj[b * C_ + kc * 32 + t] = s * (1.0f / HWD_);
    }
}

// ---- kernel 2: Afrag[b] = bf16(adj .* s_b) in fragment order; exp paid once
__global__ __launch_bounds__(256) void aprep_kernel(const float* __restrict__ adj,
                                                    const float* __restrict__ cadj,
                                                    bf16x8* __restrict__ afrag) {
    const int b = blockIdx.x, kc = blockIdx.y;
    const int t = threadIdx.x, lane = t & 63, wq = t >> 6;
    const int quad = lane >> 4, lm = lane & 15;

    __shared__ float sca[C_];
    sca[t] = cadj[b * C_ + t];
    __syncthreads();

    const int kb = kc * 32 + quad * 8;
    bf16x8* dst = afrag + ((size_t)(b * KC_ + kc) * IT_) * 64 + lane;

#pragma unroll
    for (int r = 0; r < 4; ++r) {
        const int it = wq * 4 + r;
        const int i  = it * 16 + lm;
        const float4* ap = (const float4*)(adj + (size_t)i * C_ + kb);
        float4 a0 = ap[0], a1 = ap[1];
        const float ca_i = sca[i];
        bf16x8 pk;
#pragma unroll
        for (int j = 0; j < 8; ++j) {
            float av = (j < 4) ? (&a0.x)[j] : (&a1.x)[j - 4];
            float d  = sca[kb + j] - ca_i;
            float e  = __expf(-fabsf(d));
            float s  = 2.f * e / (1.f + e);      // == 1 - 2*|sigmoid(d)-0.5|, symmetric
            pk[j] = (__bf16)(av * s);
        }
        dst[(size_t)it * 64] = pk;               // coalesced
    }
}

// ---- kernel 3: pure MFMA GEMM, operands loaded global->register in fragment order
__global__ __launch_bounds__(256) void gemm_kernel(const bf16x8* __restrict__ afrag,
                                                   const bf16x8* __restrict__ bfrag,
                                                   const float* __restrict__ para,
                                                   float* __restrict__ out) {
    const int mt = blockIdx.x;   // 0..1
    const int nt = blockIdx.y;   // 0..2
    const int b  = blockIdx.z;
    const int i0 = mt * 128, n0 = nt * 128;

    const int t = threadIdx.x, lane = t & 63, w = t >> 6;
    const int wm = w & 1, wn = w >> 1;
    const int lm = lane & 15, quad = lane >> 4;

    const bf16x8* abase = afrag + (size_t)b * KC_ * IT_ * 64 + (size_t)(mt * 8 + wm * 4) * 64 + lane;
    const bf16x8* bbase = bfrag + (size_t)b * KC_ * NT_ * 64 + (size_t)(nt * 8 + wn * 4) * 64 + lane;

    f32x4 acc[4][4];
#pragma unroll
    for (int mm = 0; mm < 4; ++mm)
#pragma unroll
        for (int nn = 0; nn < 4; ++nn)
            acc[mm][nn] = (f32x4){0.f, 0.f, 0.f, 0.f};

#pragma unroll
    for (int kc = 0; kc < KC_; ++kc) {
        bf16x8 af[4], bfr[4];
#pragma unroll
        for (int mm = 0; mm < 4; ++mm) af[mm] = abase[(size_t)(kc * IT_ + mm) * 64];
#pragma unroll
        for (int nn = 0; nn < 4; ++nn) bfr[nn] = bbase[(size_t)(kc * NT_ + nn) * 64];
#pragma unroll
        for (int mm = 0; mm < 4; ++mm)
#pragma unroll
            for (int nn = 0; nn < 4; ++nn)
                acc[mm][nn] = __builtin_amdgcn_mfma_f32_16x16x32_bf16(
                    af[mm], bfr[nn], acc[mm][nn], 0, 0, 0);
    }

#pragma unroll
    for (int mm = 0; mm < 4; ++mm) {
#pragma unroll
        for (int r = 0; r < 4; ++r) {
            const int i = i0 + wm * 64 + mm * 16 + quad * 4 + r;
            const float* pp = para + (size_t)i * HWD_;
            float* op = out + ((size_t)b * C_ + i) * HWD_;
#pragma unroll
            for (int nn = 0; nn < 4; ++nn) {
                const int n = n0 + wn * 64 + nn * 16 + lm;
                float v = acc[mm][nn][r] * pp[n];
                op[n] = v > 0.f ? v : 0.f;
            }
        }
    }
}

// ================= fallback path (R1, proven) for small ws =================
__global__ __launch_bounds__(256) void mean_kernel(const float* __restrict__ x,
                                                   float* __restrict__ cadj) {
    const int row  = (blockIdx.x << 2) + (threadIdx.x >> 6);
    const int lane = threadIdx.x & 63;
    const float2* p = (const float2*)(x + (size_t)row * HWD_);
    float s = 0.f;
#pragma unroll
    for (int tt = 0; tt < 3; ++tt) {
        float2 v = p[lane + (tt << 6)];
        s += v.x + v.y;
    }
#pragma unroll
    for (int off = 32; off; off >>= 1) s += __shfl_xor(s, off, 64);
    if (lane == 0) cadj[row] = s * (1.0f / HWD_);
}

__global__ __launch_bounds__(256) void gemm_fb(const float* __restrict__ x,
                                               const float* __restrict__ adj,
                                               const float* __restrict__ para,
                                               const float* __restrict__ cadj,
                                               float* __restrict__ out) {
    const int mt = blockIdx.x, nt = blockIdx.y, b = blockIdx.z;
    const int i0 = mt * 128, n0 = nt * 128;
    __shared__ __bf16 As[128][40];
    __shared__ __bf16 Bs[128][40];
    const int tid = threadIdx.x, lane = tid & 63, w = tid >> 6;
    const int wm = w & 1, wn = w >> 1, lm = lane & 15, quad = lane >> 4;
    const float* ca = cadj + b * C_;
    const int a_row = tid >> 1, a_half = tid & 1;
    const float ca_i = ca[i0 + a_row];
    const int b_n = tid & 127, b_jg = tid >> 7;
    f32x4 acc[4][4];
#pragma unroll
    for (int mm = 0; mm < 4; ++mm)
#pragma unroll
        for (int nn = 0; nn < 4; ++nn) acc[mm][nn] = (f32x4){0.f, 0.f, 0.f, 0.f};
    for (int k0 = 0; k0 < C_; k0 += 32) {
        __syncthreads();
        {
            const float* ap = adj + (size_t)(i0 + a_row) * C_ + k0 + a_half * 16;
            float4 av[4];
#pragma unroll
            for (int q = 0; q < 4; ++q) av[q] = ((const float4*)ap)[q];
            bf16x8 pk0, pk1;
#pragma unroll
            for (int jj = 0; jj < 16; ++jj) {
                float aval = ((const float*)av)[jj];
                float d = ca[k0 + a_half * 16 + jj] - ca_i;
                float tt = __expf(-fabsf(d));
                float s = 2.f * tt / (1.f + tt);
                float v = aval * s;
                if (jj < 8) pk0[jj & 7] = (__bf16)v; else pk1[jj & 7] = (__bf16)v;
            }
            *(bf16x8*)&As[a_row][a_half * 16]     = pk0;
            *(bf16x8*)&As[a_row][a_half * 16 + 8] = pk1;
        }
        {
            const float* xp = x + (size_t)(b * C_ + k0 + b_jg * 16) * HWD_ + n0 + b_n;
            bf16x8 pk0, pk1;
#pragma unroll
            for (int jj = 0; jj < 16; ++jj) {
                float v = xp[(size_t)jj * HWD_];
                if (jj < 8) pk0[jj & 7] = (__bf16)v; else pk1[jj & 7] = (__bf16)v;
            }
            *(bf16x8*)&Bs[b_n][b_jg * 16]     = pk0;
            *(bf16x8*)&Bs[b_n][b_jg * 16 + 8] = pk1;
        }
        __syncthreads();
        bf16x8 af[4], bfr[4];
#pragma unroll
        for (int mm = 0; mm < 4; ++mm) af[mm] = *(const bf16x8*)&As[wm * 64 + mm * 16 + lm][quad * 8];
#pragma unroll
        for (int nn = 0; nn < 4; ++nn) bfr[nn] = *(const bf16x8*)&Bs[wn * 64 + nn * 16 + lm][quad * 8];
#pragma unroll
        for (int mm = 0; mm < 4; ++mm)
#pragma unroll
            for (int nn = 0; nn < 4; ++nn)
                acc[mm][nn] = __builtin_amdgcn_mfma_f32_16x16x32_bf16(af[mm], bfr[nn], acc[mm][nn], 0, 0, 0);
    }
#pragma unroll
    for (int mm = 0; mm < 4; ++mm)
#pragma unroll
        for (int r = 0; r < 4; ++r) {
            const int i = i0 + wm * 64 + mm * 16 + quad * 4 + r;
            const float* pp = para + (size_t)i * HWD_;
            float* op = out + ((size_t)b * C_ + i) * HWD_;
#pragma unroll
            for (int nn = 0; nn < 4; ++nn) {
                const int n = n0 + wn * 64 + nn * 16 + lm;
                float v = acc[mm][nn][r] * pp[n];
                op[n] = v > 0.f ? v : 0.f;
            }
        }
}

extern "C" void kernel_launch(void* const* d_in, const int* in_sizes, int n_in,
                              void* d_out, int out_size, void* d_ws, size_t ws_size,
                              hipStream_t stream) {
    const float* x    = (const float*)d_in[0];
    const float* adj  = (const float*)d_in[1];
    const float* para = (const float*)d_in[2];
    float* out = (float*)d_out;

    if (ws_size >= WS_NEEDED) {
        float*  cadj  = (float*)d_ws;
        bf16x8* afrag = (bf16x8*)((char*)d_ws + CADJ_BYTES);
        bf16x8* bfrag = (bf16x8*)((char*)d_ws + CADJ_BYTES + AFRAG_BYTES);
        bprep_kernel<<<dim3(B_, KC_), 256, 0, stream>>>(x, cadj, bfrag);
        aprep_kernel<<<dim3(B_, KC_), 256, 0, stream>>>(adj, cadj, afrag);
        gemm_kernel<<<dim3(2, 3, B_), 256, 0, stream>>>(afrag, bfrag, para, out);
    } else {
        float* cadj = (float*)d_ws;
        mean_kernel<<<dim3((B_ * C_) / 4), 256, 0, stream>>>(x, cadj);
        gemm_fb<<<dim3(2, 3, B_), 256, 0, stream>>>(x, adj, para, cadj, out);
    }
}